// Round 1
// baseline (320.182 us; speedup 1.0000x reference)
//
#include <hip/hip_runtime.h>
#include <stdint.h>
#include <math.h>

// ---------------------------------------------------------------------------
// GAT + PairNorm + ReLU, MI355X (gfx950).  Round 9.
// R8 analysis: k_gemm 43us with MfmaUtil 13 / VALUBusy 21 / HBM 28% ->
// latency+staging bound, not a roofline. Changes:
//  * k_gemm staging: register round-trip (uint4 -> VGPR -> ds_write)
//    replaced with __builtin_amdgcn_global_load_lds width=16 (guide
//    Common-mistake #1; m193 A/B +67% on staging-bound 128^2 GEMM).
//    LDS layout was already linear tid*16B -> drop-in, bit-identical.
//  * k_scan rewritten: 30-round dependent-load chain on ONE CU ->
//    load-all (128 contiguous counts/thread), one block scan, one write
//    pass. off[N] = ETOT is a constant.
//  * Launch fusion (13 -> 9 dispatches): {cvtW+dropout+hist} -> k_pre;
//    scan runs as block 940 of the gemm launch (hist hoisted before, so
//    counts ready; scan hides under gemm's 940 blocks);
//    {dotsum+scatter} -> k_mid.
// RNG: JAX partitionable threefry (fold-like split; bits = o0^o1).
// ---------------------------------------------------------------------------

#define N_NODES 30000
#define MPAD    30080
#define DIM     512
#define NEDGE   300000
#define ETOT    330000
#define AGG_BLOCKS 7500
#define RED_BLOCKS 60
#define RED_ROWS   125

#define GEMM_BLOCKS 940
#define CVT_BLOCKS  256
#define DROP_BLOCKS 7520
#define HIST_BLOCKS 1290
#define DOT_BLOCKS  118

typedef unsigned int u32;
typedef unsigned short u16;

typedef __attribute__((ext_vector_type(8))) short bf16x8;
typedef __attribute__((ext_vector_type(4))) float f32x4;

// ----------------------------- threefry2x32 --------------------------------
__host__ __device__ __forceinline__ void threefry2x32(u32 k0, u32 k1, u32 x0, u32 x1,
                                                      u32& o0, u32& o1) {
  u32 ks2 = k0 ^ k1 ^ 0x1BD11BDAu;
#define TF_R(r) { x0 += x1; x1 = (x1 << r) | (x1 >> (32 - r)); x1 ^= x0; }
  x0 += k0; x1 += k1;
  TF_R(13) TF_R(15) TF_R(26) TF_R(6)
  x0 += k1; x1 += ks2 + 1u;
  TF_R(17) TF_R(29) TF_R(16) TF_R(24)
  x0 += ks2; x1 += k0 + 2u;
  TF_R(13) TF_R(15) TF_R(26) TF_R(6)
  x0 += k0; x1 += k1 + 3u;
  TF_R(17) TF_R(29) TF_R(16) TF_R(24)
  x0 += k1; x1 += ks2 + 4u;
  TF_R(13) TF_R(15) TF_R(26) TF_R(6)
  x0 += ks2; x1 += k0 + 5u;
#undef TF_R
  o0 = x0; o1 = x1;
}

__device__ __forceinline__ u32 tf_fold(u32 k0, u32 k1, u32 idx) {
  u32 a, b;
  threefry2x32(k0, k1, 0u, idx, a, b);
  return a ^ b;
}

__device__ __forceinline__ float bf2f(u32 bits16) {
  return __uint_as_float(bits16 << 16);
}
__device__ __forceinline__ u16 f2bf(float f) {   // RNE
  u32 u = __float_as_uint(f);
  return (u16)((u + 0x7fffu + ((u >> 16) & 1u)) >> 16);
}

// async global -> LDS, 16 bytes/lane. LDS dest must be linear (wave-uniform
// base + lane*16) -- our staging layout is exactly tid*16 within the buffer.
__device__ __forceinline__ void glds16(const u16* __restrict__ g, u16* l) {
  __builtin_amdgcn_global_load_lds(
      (const __attribute__((address_space(1))) unsigned int*)g,
      (__attribute__((address_space(3))) unsigned int*)l,
      16, 0, 0);
}

// ---------------- K_pre: fused cvtW + dropout + hist (independent) ---------
__global__ __launch_bounds__(256) void k_pre(const float* __restrict__ W,
                                             u16* __restrict__ Wt,
                                             const float* __restrict__ x,
                                             u16* __restrict__ xd,
                                             const int* __restrict__ ei,
                                             int* __restrict__ counts,
                                             u32 kf0, u32 kf1) {
  __shared__ u16 tile[32][33];
  int b = blockIdx.x;
  if (b < CVT_BLOCKS) {
    // ---- W (fp32) -> Wt (bf16, transposed) ----
    int bk = (b & 15) * 32, bn = (b >> 4) * 32;
    int c = threadIdx.x & 31, r = threadIdx.x >> 5;
#pragma unroll
    for (int rr = 0; rr < 32; rr += 8)
      tile[r + rr][c] = f2bf(W[(size_t)(bk + r + rr) * DIM + bn + c]);
    __syncthreads();
#pragma unroll
    for (int rr = 0; rr < 32; rr += 8)
      Wt[(size_t)(bn + r + rr) * DIM + bk + c] = tile[c][r + rr];
  } else if (b < CVT_BLOCKS + DROP_BLOCKS) {
    // ---- feature dropout (p=0.5) fp32 -> bf16, pad ----
    size_t gid = (size_t)(b - CVT_BLOCKS) * 256 + threadIdx.x;
    size_t i0 = gid * 8;
    if (i0 < (size_t)MPAD * DIM) {
      uint4 o = make_uint4(0u, 0u, 0u, 0u);
      if (i0 < (size_t)N_NODES * DIM) {
        float4 v0 = *(const float4*)(x + i0);
        float4 v1 = *(const float4*)(x + i0 + 4);
        float xv[8] = {v0.x, v0.y, v0.z, v0.w, v1.x, v1.y, v1.z, v1.w};
        u32 res[4];
#pragma unroll
        for (int p = 0; p < 4; p++) {
          u32 b0 = tf_fold(kf0, kf1, (u32)i0 + 2 * p);
          u32 b1 = tf_fold(kf0, kf1, (u32)i0 + 2 * p + 1);
          u32 r0 = (b0 >> 31) ? 0u : (u32)f2bf(2.0f * xv[2 * p]);
          u32 r1 = (b1 >> 31) ? 0u : (u32)f2bf(2.0f * xv[2 * p + 1]);
          res[p] = r0 | (r1 << 16);
        }
        o = make_uint4(res[0], res[1], res[2], res[3]);
      }
      *(uint4*)(xd + i0) = o;
    }
  } else {
    // ---- histogram of dst (with self-loops) ----
    int i = (b - CVT_BLOCKS - DROP_BLOCKS) * 256 + threadIdx.x;
    if (i < ETOT) {
      int d = (i < NEDGE) ? ei[NEDGE + i] : (i - NEDGE);
      atomicAdd(&counts[d], 1);
    }
  }
}

// --------------------- K_gemm: GEMM + fused dots + scan --------------------
// h[m][n] = sum_k xd[m][k]*Wt[n][k]. 128x128 tile, 4 waves, BK=32. Staging
// via global_load_lds (16B). Block 940 runs the counting-sort scan instead
// (hidden under the 940 gemm blocks; hist ran in k_pre).
__global__ __launch_bounds__(256) void k_gemm(const u16* __restrict__ A,
                                              const u16* __restrict__ B,
                                              u16* __restrict__ H,
                                              const float* __restrict__ atts,
                                              const float* __restrict__ attd,
                                              float* __restrict__ aspart,
                                              float* __restrict__ adpart,
                                              const int* __restrict__ counts,
                                              int* __restrict__ off,
                                              int* __restrict__ cursor) {
  __shared__ __align__(16) u16 lA[128 * 32];
  __shared__ __align__(16) u16 lB[128 * 32];
  __shared__ int xw[4];

  if (blockIdx.x >= GEMM_BLOCKS) {
    // ---------------- exclusive scan of counts (1 block) ----------------
    int tid = threadIdx.x, lane = tid & 63, wid = tid >> 6;
    int base = tid * 128;            // 256*128 = 32768 >= 30000
    int sum = 0;
    for (int j = 0; j < 128; j++) {
      int i = base + j;
      sum += (i < N_NODES) ? counts[i] : 0;
    }
    int xinc = sum;
#pragma unroll
    for (int d = 1; d < 64; d <<= 1) {
      int y = __shfl_up(xinc, d);
      if (lane >= d) xinc += y;
    }
    if (lane == 63) xw[wid] = xinc;
    __syncthreads();
    int wbase = 0;
#pragma unroll
    for (int w = 0; w < 4; w++)
      if (w < wid) wbase += xw[w];
    int run = wbase + xinc - sum;    // exclusive base for this thread
    for (int j = 0; j < 128; j++) {
      int i = base + j;
      if (i < N_NODES) {
        off[i] = run;
        cursor[i] = run;
        run += counts[i];
      }
    }
    if (tid == 0) off[N_NODES] = ETOT;
    return;
  }

  const int bn = (blockIdx.x & 3) * 128;
  const int bm = (blockIdx.x >> 2) * 128;
  const int tid = threadIdx.x;
  const int wave = tid >> 6, lane = tid & 63;
  const int quad = lane >> 4, l16 = lane & 15;
  const int wrow = (wave & 1) * 64, wcol = (wave >> 1) * 64;

  f32x4 acc[4][4] = {};
  const int srow = tid >> 2;
  const int scq  = (tid & 3) * 8;

  const u16* gA0 = A + (size_t)(bm + srow) * DIM + scq;
  const u16* gA1 = A + (size_t)(bm + 64 + srow) * DIM + scq;
  const u16* gB0 = B + (size_t)(bn + srow) * DIM + scq;
  const u16* gB1 = B + (size_t)(bn + 64 + srow) * DIM + scq;
  u16* sA0 = lA + srow * 32 + scq;
  u16* sA1 = lA + (64 + srow) * 32 + scq;
  u16* sB0 = lB + srow * 32 + scq;
  u16* sB1 = lB + (64 + srow) * 32 + scq;

  for (int k0 = 0; k0 < DIM; k0 += 32) {
    __syncthreads();                  // prior MFMA ds_reads done
    glds16(gA0 + k0, sA0);
    glds16(gA1 + k0, sA1);
    glds16(gB0 + k0, sB0);
    glds16(gB1 + k0, sB1);
    __syncthreads();                  // vmcnt(0) drain -> LDS ready

    bf16x8 af[4], bfr[4];
#pragma unroll
    for (int i = 0; i < 4; i++)
      af[i] = *(const bf16x8*)(lA + (wrow + i * 16 + l16) * 32 + quad * 8);
#pragma unroll
    for (int j = 0; j < 4; j++)
      bfr[j] = *(const bf16x8*)(lB + (wcol + j * 16 + l16) * 32 + quad * 8);
#pragma unroll
    for (int i = 0; i < 4; i++)
#pragma unroll
      for (int j = 0; j < 4; j++)
        acc[i][j] = __builtin_amdgcn_mfma_f32_16x16x32_bf16(af[i], bfr[j], acc[i][j], 0, 0, 0);
  }

  // ---- epilogue: H write (C/D: col=lane&15, row=quad*4+reg) ----
#pragma unroll
  for (int i = 0; i < 4; i++) {
#pragma unroll
    for (int r = 0; r < 4; r++) {
      int row = bm + wrow + i * 16 + quad * 4 + r;
      u16* hp = H + (size_t)row * DIM + bn + wcol + l16;
#pragma unroll
      for (int j = 0; j < 4; j++) hp[j * 16] = f2bf(acc[i][j][r]);
    }
  }

  // ---- fused attention dots: partial over this wave's 64 cols ----
  float as_j[4], ad_j[4];
#pragma unroll
  for (int j = 0; j < 4; j++) {
    int col = bn + wcol + j * 16 + l16;
    as_j[j] = atts[col];
    ad_j[j] = attd[col];
  }
  int slot = ((bn >> 7) << 1) + (wcol >> 6);   // 0..7
#pragma unroll
  for (int i = 0; i < 4; i++) {
#pragma unroll
    for (int r = 0; r < 4; r++) {
      float ps = acc[i][0][r] * as_j[0] + acc[i][1][r] * as_j[1]
               + acc[i][2][r] * as_j[2] + acc[i][3][r] * as_j[3];
      float pd = acc[i][0][r] * ad_j[0] + acc[i][1][r] * ad_j[1]
               + acc[i][2][r] * ad_j[2] + acc[i][3][r] * ad_j[3];
#pragma unroll
      for (int d = 1; d < 16; d <<= 1) {
        ps += __shfl_xor(ps, d);
        pd += __shfl_xor(pd, d);
      }
      int row = bm + wrow + i * 16 + quad * 4 + r;
      if (l16 == 0) {
        aspart[slot * MPAD + row] = ps;
        adpart[slot * MPAD + row] = pd;
      }
    }
  }
}

// -------------- K_mid: fused dotsum + scatter (independent) ----------------
__global__ __launch_bounds__(256) void k_mid(const float* __restrict__ aspart,
                                             const float* __restrict__ adpart,
                                             float* __restrict__ a_s,
                                             float* __restrict__ a_d,
                                             const int* __restrict__ ei,
                                             int* __restrict__ cursor,
                                             int* __restrict__ perm) {
  int b = blockIdx.x;
  if (b < DOT_BLOCKS) {
    int i = b * 256 + threadIdx.x;
    if (i < N_NODES) {
      float s = 0.f, d = 0.f;
#pragma unroll
      for (int k = 0; k < 8; k++) {
        s += aspart[k * MPAD + i];
        d += adpart[k * MPAD + i];
      }
      a_s[i] = s;
      a_d[i] = d;
    }
  } else {
    int i = (b - DOT_BLOCKS) * 256 + threadIdx.x;
    if (i < ETOT) {
      int d = (i < NEDGE) ? ei[NEDGE + i] : (i - NEDGE);
      int slot = atomicAdd(&cursor[d], 1);
      perm[slot] = i;
    }
  }
}

// ----- K7: segment softmax + attention dropout + aggregation + stats -------
// oa stored bf16; column/ssq stats computed on the quantized values.
__global__ __launch_bounds__(256) void k_aggregate(
    const int* __restrict__ ei, const int* __restrict__ off, const int* __restrict__ perm,
    const float* __restrict__ a_s, const float* __restrict__ a_d,
    const u16* __restrict__ h, const float* __restrict__ bias,
    u16* __restrict__ oa, float* __restrict__ colpart,
    float* __restrict__ ssqpart, u32 ka0, u32 ka1) {
  __shared__ float lbuf[4][512];
  int wid = threadIdx.x >> 6;
  int node = blockIdx.x * 4 + wid;
  int lane = threadIdx.x & 63;
  int beg = off[node], end = off[node + 1];
  int deg = end - beg;
  float adn = a_d[node];

  float acc[8] = {0.f, 0.f, 0.f, 0.f, 0.f, 0.f, 0.f, 0.f};

  if (deg <= 64) {
    int idx = beg + lane;
    bool valid = idx < end;
    int s = 0;
    float lg = -3.0e38f;
    u32 keepbits = 0;
    if (valid) {
      int eid = perm[idx];
      s = (eid < NEDGE) ? ei[eid] : (eid - NEDGE);
      lg = a_s[s] + adn;
      lg = (lg < 0.f) ? 0.2f * lg : lg;
      keepbits = tf_fold(ka0, ka1, (u32)eid);
    }
    float mx = lg;
#pragma unroll
    for (int d = 1; d < 64; d <<= 1) mx = fmaxf(mx, __shfl_xor(mx, d));
    float ee = valid ? expf(lg - mx) : 0.f;
    float ssum = ee;
#pragma unroll
    for (int d = 1; d < 64; d <<= 1) ssum += __shfl_xor(ssum, d);
    float inv_s = 2.5f / (ssum + 1e-16f);
    float w = (valid && ((keepbits >> 9) < 3355444u)) ? ee * inv_s : 0.f;

    for (int j = 0; j < deg; j++) {
      float wj = __shfl(w, j);
      if (wj != 0.f) {
        int sj = __shfl(s, j);
        uint4 hv = *(const uint4*)(h + (size_t)sj * DIM + lane * 8);
        u32 hw[4] = {hv.x, hv.y, hv.z, hv.w};
#pragma unroll
        for (int p = 0; p < 4; p++) {
          acc[2 * p]     += wj * bf2f(hw[p] & 0xffffu);
          acc[2 * p + 1] += wj * bf2f(hw[p] >> 16);
        }
      }
    }
  } else {
    float mx = -3.0e38f;
    for (int base = beg; base < end; base += 64) {
      int idx = base + lane;
      if (idx < end) {
        int eid = perm[idx];
        int s = (eid < NEDGE) ? ei[eid] : (eid - NEDGE);
        float lg = a_s[s] + adn;
        lg = (lg < 0.f) ? 0.2f * lg : lg;
        mx = fmaxf(mx, lg);
      }
    }
#pragma unroll
    for (int d = 1; d < 64; d <<= 1) mx = fmaxf(mx, __shfl_xor(mx, d));
    float ssum = 0.f;
    for (int base = beg; base < end; base += 64) {
      int idx = base + lane;
      if (idx < end) {
        int eid = perm[idx];
        int s = (eid < NEDGE) ? ei[eid] : (eid - NEDGE);
        float lg = a_s[s] + adn;
        lg = (lg < 0.f) ? 0.2f * lg : lg;
        ssum += expf(lg - mx);
      }
    }
#pragma unroll
    for (int d = 1; d < 64; d <<= 1) ssum += __shfl_xor(ssum, d);
    float inv_s = 2.5f / (ssum + 1e-16f);
    for (int base = beg; base < end; base += 64) {
      int idx = base + lane;
      float w = 0.f; int s = 0;
      if (idx < end) {
        int eid = perm[idx];
        s = (eid < NEDGE) ? ei[eid] : (eid - NEDGE);
        float lg = a_s[s] + adn;
        lg = (lg < 0.f) ? 0.2f * lg : lg;
        float ee = expf(lg - mx);
        u32 bits = tf_fold(ka0, ka1, (u32)eid);
        if ((bits >> 9) < 3355444u) w = ee * inv_s;
      }
      int cnt = min(64, end - base);
      for (int j = 0; j < cnt; j++) {
        float wj = __shfl(w, j);
        if (wj != 0.f) {
          int sj = __shfl(s, j);
          uint4 hv = *(const uint4*)(h + (size_t)sj * DIM + lane * 8);
          u32 hw[4] = {hv.x, hv.y, hv.z, hv.w};
#pragma unroll
          for (int p = 0; p < 4; p++) {
            acc[2 * p]     += wj * bf2f(hw[p] & 0xffffu);
            acc[2 * p + 1] += wj * bf2f(hw[p] >> 16);
          }
        }
      }
    }
  }

  // epilogue: add bias, quantize to bf16, store oa, stats on quantized vals
  float4 b0 = *(const float4*)(bias + lane * 8);
  float4 b1 = *(const float4*)(bias + lane * 8 + 4);
  float bb[8] = {b0.x, b0.y, b0.z, b0.w, b1.x, b1.y, b1.z, b1.w};
  u32 res[4];
  float vq[8];
#pragma unroll
  for (int p = 0; p < 4; p++) {
    u16 q0 = f2bf(acc[2 * p]     + bb[2 * p]);
    u16 q1 = f2bf(acc[2 * p + 1] + bb[2 * p + 1]);
    res[p] = (u32)q0 | ((u32)q1 << 16);
    vq[2 * p]     = bf2f(q0);
    vq[2 * p + 1] = bf2f(q1);
  }
  *(uint4*)(oa + (size_t)node * DIM + lane * 8) = make_uint4(res[0], res[1], res[2], res[3]);
  *(float4*)&lbuf[wid][lane * 8]     = make_float4(vq[0], vq[1], vq[2], vq[3]);
  *(float4*)&lbuf[wid][lane * 8 + 4] = make_float4(vq[4], vq[5], vq[6], vq[7]);
  __syncthreads();

  int t = threadIdx.x;
  float s0 = 0.f, s1 = 0.f, ssl = 0.f;
#pragma unroll
  for (int w = 0; w < 4; w++) {
    float a = lbuf[w][t], b = lbuf[w][t + 256];
    s0 += a; s1 += b;
    ssl = fmaf(a, a, ssl);
    ssl = fmaf(b, b, ssl);
  }
  colpart[(size_t)blockIdx.x * 512 + t]       = s0;
  colpart[(size_t)blockIdx.x * 512 + 256 + t] = s1;
#pragma unroll
  for (int d = 1; d < 64; d <<= 1) ssl += __shfl_xor(ssl, d);
  __shared__ float wss[4];
  if ((t & 63) == 0) wss[t >> 6] = ssl;
  __syncthreads();
  if (t == 0) ssqpart[blockIdx.x] = wss[0] + wss[1] + wss[2] + wss[3];
}

// ------------- K8: reduce column partials + ssq (depth-60 atomics) ---------
__global__ __launch_bounds__(256) void k_redstats(const float* __restrict__ colpart,
                                                  const float* __restrict__ ssqpart,
                                                  float* __restrict__ colsum,
                                                  double* __restrict__ ssq) {
  int b = blockIdx.x;
  int t = threadIdx.x;
  int r0 = b * RED_ROWS;
  float s0 = 0.f, s1 = 0.f;
  for (int r = r0; r < r0 + RED_ROWS; r++) {
    s0 += colpart[(size_t)r * 512 + t];
    s1 += colpart[(size_t)r * 512 + 256 + t];
  }
  atomicAdd(&colsum[t], s0);
  atomicAdd(&colsum[t + 256], s1);
  float sl = (t < RED_ROWS) ? ssqpart[r0 + t] : 0.f;
#pragma unroll
  for (int d = 1; d < 64; d <<= 1) sl += __shfl_xor(sl, d);
  __shared__ float w4[4];
  if ((t & 63) == 0) w4[t >> 6] = sl;
  __syncthreads();
  if (t == 0) atomicAdd(ssq, (double)(w4[0] + w4[1] + w4[2] + w4[3]));
}

// --------------------------- K9: finalize scalars --------------------------
__global__ __launch_bounds__(512) void k_finalize(const float* __restrict__ colsum,
                                                  const double* __restrict__ ssq,
                                                  float* __restrict__ mu,
                                                  float* __restrict__ invp) {
  __shared__ double sred[8];
  int j = threadIdx.x;
  float m = colsum[j] * (1.0f / 30000.0f);
  mu[j] = m;
  double p = (double)m * (double)m;
#pragma unroll
  for (int d = 1; d < 64; d <<= 1) p += __shfl_xor(p, d);
  int lane = j & 63, wid = j >> 6;
  if (lane == 0) sred[wid] = p;
  __syncthreads();
  if (j == 0) {
    double smu2 = 0.0;
#pragma unroll
    for (int w = 0; w < 8; w++) smu2 += sred[w];
    double centered = ssq[0] - 30000.0 * smu2;
    double mean = centered * (1.0 / 30000.0);
    if (!(mean >= 0.0)) mean = 0.0;
    float rn = sqrtf(1e-6f + (float)mean);
    invp[0] = 1.0f / rn;
  }
}

// ---------------- K10: center, scale, relu (bf16 oa -> fp32 out) -----------
__global__ __launch_bounds__(256) void k_finalout(const u16* __restrict__ oa,
                                                  const float* __restrict__ mu,
                                                  const float* __restrict__ invp,
                                                  float* __restrict__ out) {
  size_t gid = (size_t)blockIdx.x * 256 + threadIdx.x;
  size_t i0 = gid * 8;
  if (i0 >= (size_t)N_NODES * DIM) return;
  float inv = invp[0];
  int j = (int)(i0 & (DIM - 1));
  uint4 v = *(const uint4*)(oa + i0);
  u32 w[4] = {v.x, v.y, v.z, v.w};
  float o[8];
#pragma unroll
  for (int p = 0; p < 4; p++) {
    float z0 = (bf2f(w[p] & 0xffffu) - mu[j + 2 * p]) * inv;
    float z1 = (bf2f(w[p] >> 16)     - mu[j + 2 * p + 1]) * inv;
    o[2 * p]     = (z0 < 0.f) ? 0.f : z0;
    o[2 * p + 1] = (z1 < 0.f) ? 0.f : z1;
  }
  *(float4*)(out + i0)     = make_float4(o[0], o[1], o[2], o[3]);
  *(float4*)(out + i0 + 4) = make_float4(o[4], o[5], o[6], o[7]);
}

// ---------------------------------------------------------------------------
extern "C" void kernel_launch(void* const* d_in, const int* in_sizes, int n_in,
                              void* d_out, int out_size, void* d_ws, size_t ws_size,
                              hipStream_t stream) {
  const float* x    = (const float*)d_in[0];
  const int*   ei   = (const int*)d_in[1];
  const float* W    = (const float*)d_in[2];
  const float* atts = (const float*)d_in[3];
  const float* attd = (const float*)d_in[4];
  const float* bias = (const float*)d_in[5];
  float* out = (float*)d_out;
  char* ws = (char*)d_ws;

  // oa is bf16 and overlays xd at ws+0 (xd dead after gemm, oa written
  // by aggregate). aspart/adpart live in the dead gap [32M, 61.4M) between
  // gemm (writes them) and aggregate; k_mid consumes them first.
  u16*   xd      = (u16*)(ws + 0);             // 30,801,920
  u16*   oa      = (u16*)(ws + 0);             // 30,720,000 (overlay)
  float* aspart  = (float*)(ws + 32000000);    // 8*30080*4 = 962,560
  float* adpart  = (float*)(ws + 33000000);    //   962,560
  u16*   h       = (u16*)(ws + 61440000);      // 30,801,920
  u16*   Wt      = (u16*)(ws + 92241920);      //    524,288
  float* a_s     = (float*)(ws + 92766208);    //    120,064
  float* a_d     = (float*)(ws + 92886272);    //    120,064
  int*   counts  = (int*)(ws + 93006336);
  int*   offs    = (int*)(ws + 93126400);
  int*   cursor  = (int*)(ws + 93246464);
  int*   perm    = (int*)(ws + 93366528);      //  1,320,000
  float* colsum  = (float*)(ws + 94686528);
  float* mu      = (float*)(ws + 94688576);
  double* ssq    = (double*)(ws + 94690624);
  float* invp    = (float*)(ws + 94690688);    // end 94,690,752

  float* colpart = out;                        // d_out scratch until finalout
  float* ssqpart = out + (size_t)AGG_BLOCKS * 512;

  u32 kf0, kf1, ka0, ka1;
  threefry2x32(0u, 42u, 0u, 0u, kf0, kf1);
  threefry2x32(0u, 42u, 0u, 1u, ka0, ka1);

  hipMemsetAsync(counts, 0, 120064, stream);
  hipMemsetAsync((void*)colsum, 0, 4224, stream);

  // L1: cvtW + dropout + hist (all independent; counts memset above)
  k_pre<<<CVT_BLOCKS + DROP_BLOCKS + HIST_BLOCKS, 256, 0, stream>>>(
      W, Wt, x, xd, ei, counts, kf0, kf1);
  // L2: gemm (940 blocks) + scan (block 940, hidden under gemm)
  k_gemm<<<GEMM_BLOCKS + 1, 256, 0, stream>>>(xd, Wt, h, atts, attd,
                                              aspart, adpart, counts, offs, cursor);
  // L3: dotsum (needs gemm) + scatter (needs scan) -- independent chains
  k_mid<<<DOT_BLOCKS + HIST_BLOCKS, 256, 0, stream>>>(aspart, adpart, a_s, a_d,
                                                      ei, cursor, perm);
  k_aggregate<<<AGG_BLOCKS, 256, 0, stream>>>(ei, offs, perm, a_s, a_d, h, bias,
                                              oa, colpart, ssqpart, ka0, ka1);
  k_redstats<<<RED_BLOCKS, 256, 0, stream>>>(colpart, ssqpart, colsum, ssq);
  k_finalize<<<1, 512, 0, stream>>>(colsum, ssq, mu, invp);
  k_finalout<<<7500, 256, 0, stream>>>(oa, mu, invp, out);
}